// Round 6
// baseline (329.777 us; speedup 1.0000x reference)
//
#include <hip/hip_runtime.h>
#include <math.h>

#define DIM 64
#define TILE 64
#define LDK 72   // padded k-stride in bf16 units (144 B, 16B-aligned quads)

typedef __attribute__((ext_vector_type(8))) short short8v;   // 8 bf16 = 4 VGPR
typedef __attribute__((ext_vector_type(4))) float floatx4;   // MFMA acc

struct ushort4s { unsigned short x, y, z, w; };

__device__ __forceinline__ float softplus_fast(float z) {
    // softplus(z) = max(z,0) + log(1+exp(-|z|)); hardware exp/log
    return fmaxf(z, 0.f) + __logf(1.f + __expf(-fabsf(z)));
}

__device__ __forceinline__ unsigned short f2bf(float x) {
    // fp32 -> bf16 round-to-nearest-even
    unsigned u = __builtin_bit_cast(unsigned, x);
    return (unsigned short)((u + 0x7fffu + ((u >> 16) & 1u)) >> 16);
}

// ---- single fused kernel: bf16 MFMA noise-GEMM + softplus + target terms +
// ---- last-block finalize (threadfence-reduction pattern) ----
__global__ __launch_bounds__(256, 6) void nce_main_kernel(
    const float* __restrict__ inp, const float* __restrict__ embs,
    const int* __restrict__ tgt, const int* __restrict__ ns,
    const float* __restrict__ lpn, float cadd, int nColTiles, int nBlocks,
    float invRows, int* __restrict__ ticket, float* __restrict__ partials,
    float* __restrict__ out)
{
    __shared__ unsigned short A_lds[TILE * LDK];  // A[row][k] bf16
    __shared__ unsigned short B_lds[TILE * LDK];  // B[col][k] bf16
    __shared__ float cks[TILE];
    __shared__ float red[4];
    __shared__ int amLast;

    int tid = threadIdx.x;
    int wave = tid >> 6, lane = tid & 63;
    int rowTile = blockIdx.x / nColTiles;
    int colTile = blockIdx.x % nColTiles;
    int rBase = rowTile * TILE;
    int cBase = colTile * TILE;

    float s = 0.f;

    // ---- stage A (input rows) as bf16 into LDS ----
    const float4* Ag4 = (const float4*)(inp + (size_t)rBase * DIM);
    #pragma unroll
    for (int c = 0; c < 4; ++c) {
        int f = c * 256 + tid;          // 1024 float4s = 64 rows x 16 quads
        int row = f >> 4;
        int kq = f & 15;
        float4 v = Ag4[f];
        ushort4s b = { f2bf(v.x), f2bf(v.y), f2bf(v.z), f2bf(v.w) };
        *(ushort4s*)&A_lds[row * LDK + kq * 4] = b;
    }
    // ---- stage B (gathered noise embeddings) as bf16 into LDS ----
    #pragma unroll
    for (int c = 0; c < 4; ++c) {
        int f = c * 256 + tid;
        int col = f >> 4;
        int kq = f & 15;
        int item = ns[cBase + col];
        float4 v = ((const float4*)(embs + (size_t)item * DIM))[kq];
        ushort4s b = { f2bf(v.x), f2bf(v.y), f2bf(v.z), f2bf(v.w) };
        *(ushort4s*)&B_lds[col * LDK + kq * 4] = b;
    }
    if (tid < TILE) cks[tid] = cadd - lpn[ns[cBase + tid]];

    // ---- target terms: 4 rows per block, wave 0 only (overlaps staging) ----
    if (wave == 0) {
        int row = rBase + colTile * 4 + (lane >> 4);
        int t = tgt[row];
        float4 e = ((const float4*)(embs + (size_t)t * DIM))[lane & 15];
        float4 a = ((const float4*)(inp + (size_t)row * DIM))[lane & 15];
        float p = a.x * e.x + a.y * e.y + a.z * e.z + a.w * e.w;
        p += __shfl_xor(p, 1);
        p += __shfl_xor(p, 2);
        p += __shfl_xor(p, 4);
        p += __shfl_xor(p, 8);
        if ((lane & 15) == 0) {
            float x0 = p + cadd - lpn[t];
            s += softplus_fast(-x0);   // BCE label 1 == softplus(-x0)
        }
    }
    __syncthreads();

    // ---- MFMA: each wave computes 16 rows x 64 cols ----
    int ar = wave * 16 + (lane & 15);
    int ak = (lane >> 4) * 8;
    short8v a0 = *(const short8v*)&A_lds[ar * LDK + ak];        // k = 0..31
    short8v a1 = *(const short8v*)&A_lds[ar * LDK + 32 + ak];   // k = 32..63

    #pragma unroll
    for (int cf = 0; cf < 4; ++cf) {
        int bc = cf * 16 + (lane & 15);
        short8v b0 = *(const short8v*)&B_lds[bc * LDK + ak];
        short8v b1 = *(const short8v*)&B_lds[bc * LDK + 32 + ak];
        floatx4 acc = {0.f, 0.f, 0.f, 0.f};
        acc = __builtin_amdgcn_mfma_f32_16x16x32_bf16(a0, b0, acc, 0, 0, 0);
        acc = __builtin_amdgcn_mfma_f32_16x16x32_bf16(a1, b1, acc, 0, 0, 0);
        float ck = cks[cf * 16 + (lane & 15)];   // C-layout: col = lane&15
        #pragma unroll
        for (int j = 0; j < 4; ++j)
            s += softplus_fast(acc[j] + ck);     // BCE label 0 == softplus(x)
    }

    // ---- block reduction ----
    #pragma unroll
    for (int off = 32; off > 0; off >>= 1) s += __shfl_xor(s, off);
    if (lane == 0) red[wave] = s;
    __syncthreads();

    // ---- publish partial; last block finalizes ----
    if (tid == 0) {
        partials[blockIdx.x] = red[0] + red[1] + red[2] + red[3];
        __threadfence();                       // partial visible device-wide
        int old = atomicAdd(ticket, 1);        // device-scope by default
        amLast = (old == nBlocks - 1);
    }
    __syncthreads();
    if (amLast) {
        __threadfence();                       // acquire: see all partials
        float t2 = 0.f;
        for (int i = tid; i < nBlocks; i += 256) t2 += partials[i];
        #pragma unroll
        for (int off = 32; off > 0; off >>= 1) t2 += __shfl_xor(t2, off);
        if (lane == 0) red[wave] = t2;
        __syncthreads();
        if (tid == 0) out[0] = (red[0] + red[1] + red[2] + red[3]) * invRows;
    }
}

extern "C" void kernel_launch(void* const* d_in, const int* in_sizes, int n_in,
                              void* d_out, int out_size, void* d_ws, size_t ws_size,
                              hipStream_t stream) {
    const int*   target = (const int*)d_in[0];
    const float* input  = (const float*)d_in[1];
    const float* embs   = (const float*)d_in[2];
    const int*   ns     = (const int*)d_in[3];
    const float* lpn    = (const float*)d_in[4];
    float* out = (float*)d_out;

    int nRows = in_sizes[0];            // B*N = 6400
    int K     = in_sizes[3];            // 1024
    long long V = in_sizes[4];          // 1,000,000
    float NORM = logf((float)V);
    float LOGK = logf((float)K);
    float cadd = -(NORM + LOGK);        // x = score + cadd - lpn[idx]

    int nRowTiles = nRows / TILE;       // 100
    int nColTiles = K / TILE;           // 16
    int nMain = nRowTiles * nColTiles;  // 1600

    int*   ticket   = (int*)d_ws;                  // ws[0]: ticket counter
    float* partials = (float*)d_ws + 64;           // 1600 block partials

    hipMemsetAsync(ticket, 0, sizeof(int), stream);   // ws is poisoned 0xAA each replay
    nce_main_kernel<<<nMain, 256, 0, stream>>>(input, embs, target, ns, lpn,
                                               cadd, nColTiles, nMain,
                                               1.0f / (float)nRows,
                                               ticket, partials, out);
}